// Round 12
// baseline (1217.237 us; speedup 1.0000x reference)
//
#include <hip/hip_runtime.h>
#include <hip/hip_bf16.h>
#include <stdint.h>

#define HH 96
#define WW 96
#define NCH 256
#define PH 95
#define PW 95
#define NP 9025          // PH*PW
#define DD 1024          // 4*NCH (bytes per row in i8)
#define FEPS 1e-8f

#define BMT 128          // target rows per block
#define BNS 256          // source cols per block
#define NTM 72           // row tiles (9216/128)
#define NTN 36           // col tiles (9216/256)
#define NPAD2 9216
#define NBLK3 2592       // NTM*NTN (divisible by 8)
#define KT 16            // DD/64
#define QSCL 508.0f
#define QS2 (1.0f / (508.0f * 508.0f))
#define DBIAS (1 << 19)  // dot bias (|dot| < 2^19)

typedef __attribute__((ext_vector_type(4))) int i32x4;
typedef __attribute__((ext_vector_type(4))) unsigned int u32x4;
typedef unsigned long long u64;
typedef unsigned int u32;
using bf16 = __hip_bfloat16;

__device__ __forceinline__ u32 umx(u32 a, u32 b) { return a > b ? a : b; }
__device__ __forceinline__ u64 umax(u64 a, u64 b) { return a > b ? a : b; }

// per-pixel partial (64-ch) sum of squares; g=blockIdx.y, img=blockIdx.z.
// Also zeroes pad rows of Sq/Tq (g==0 blocks only).
__global__ __launch_bounds__(256) void k_q(const float* __restrict__ src,
                                           const float* __restrict__ tgt,
                                           float* __restrict__ qpart,
                                           int8_t* __restrict__ Sq,
                                           int8_t* __restrict__ Tq) {
  int p = blockIdx.x * 256 + threadIdx.x;  // 36*256 == 9216 exactly
  int g = blockIdx.y;                      // channel group (4 x 64)
  const float* img = blockIdx.z ? tgt : src;
  const float* base = img + (size_t)(g * 64) * (HH * WW);
  float acc = 0.f;
  #pragma unroll 8
  for (int c = 0; c < 64; ++c) {
    float v = base[(size_t)c * (HH * WW) + p];
    acc = fmaf(v, v, acc);
  }
  qpart[((size_t)blockIdx.z * 4 + g) * (HH * WW) + p] = acc;
  if (g == 0) {  // zero pad rows NP..NPAD2 (pad dot = 0, never wins)
    const int padWords = (NPAD2 - NP) * DD / 4;  // u32 words
    u32* pw = (u32*)((blockIdx.z ? Tq : Sq) + (size_t)NP * DD);
    for (int j = p; j < padWords; j += 36 * 256) pw[j] = 0u;
  }
}

// per-patch squared norm = 4-group x 4-point sum of qpart
__global__ __launch_bounds__(256) void k_sq(const float* __restrict__ qpart,
                                            float* __restrict__ sq_s,
                                            float* __restrict__ sq_t) {
  int n = blockIdx.x * 256 + threadIdx.x;
  if (n >= NP) return;
  int y = n / PW, x = n - y * PW;
  int b = y * WW + x;
  float s = 0.f, t = 0.f;
  #pragma unroll
  for (int g = 0; g < 4; ++g) {
    const float* qs = qpart + (size_t)g * (HH * WW);
    const float* qt = qpart + (size_t)(4 + g) * (HH * WW);
    s += qs[b] + qs[b + 1] + qs[b + WW] + qs[b + WW + 1];
    t += qt[b] + qt[b + 1] + qt[b + WW] + qt[b + WW + 1];
  }
  sq_s[n] = s; sq_t[n] = t;
}

// normalized, globally-scaled i8 patch matrix [NPAD2][DD] via LDS transpose.
// Coalesced output: each thread packs 16 i8 -> one dwordx4 store.
// z = 0: (src, sq_s) -> Sq ; z = 1: (tgt, sq_t) -> Tq
__global__ __launch_bounds__(128) void k_norm(const float* __restrict__ src,
                                              const float* __restrict__ tgt,
                                              const float* __restrict__ sq_s,
                                              const float* __restrict__ sq_t,
                                              int8_t* __restrict__ Sq,
                                              int8_t* __restrict__ Tq) {
  __shared__ float tile[64 * 129];
  __shared__ float rn[PW];
  const float* img = blockIdx.z ? tgt : src;
  const float* sq = blockIdx.z ? sq_t : sq_s;
  int8_t* out = blockIdx.z ? Tq : Sq;
  int y = blockIdx.y;
  int d0 = blockIdx.x * 64;     // 16 chunks of 64 d's
  int k = d0 >> 8;              // which 2x2 shift
  int c0 = d0 & 255;
  int iy = k >> 1, jx = k & 1;
  int t = threadIdx.x;
  if (t < PW) rn[t] = QSCL / (sqrtf(sq[y * PW + t]) + FEPS);
  int x = t;
  const float* base = img + (size_t)(y + iy) * WW + jx;
  #pragma unroll 4
  for (int dl = 0; dl < 64; ++dl) {
    int c = c0 + dl;
    float v = (x < PW) ? base[(size_t)c * (HH * WW) + x] : 0.f;
    tile[dl * 129 + x] = v;
  }
  __syncthreads();
  int part = t & 3;             // 16 d's per part
  int xl0 = t >> 2;             // 32 xl per pass
  #pragma unroll
  for (int pass = 0; pass < 3; ++pass) {
    int xl = xl0 + pass * 32;
    if (xl < PW) {
      float r = rn[xl];
      u32x4 w;
      #pragma unroll
      for (int g = 0; g < 4; ++g) {
        u32 pk = 0;
        #pragma unroll
        for (int bb = 0; bb < 4; ++bb) {
          int dl = part * 16 + g * 4 + bb;
          float qv = tile[dl * 129 + xl] * r;
          qv = fminf(fmaxf(qv, -127.f), 127.f);
          pk |= ((u32)(uint8_t)(int8_t)(int)rintf(qv)) << (8 * bb);
        }
        w[g] = pk;
      }
      *(u32x4*)(out + (size_t)(y * PW + xl) * DD + d0 + part * 16) = w;
    }
  }
}

// ---- inline-asm helpers ----
#define DSR(dst, base, IMMSTR) \
  asm volatile("ds_read_b128 %0, %1 offset:" IMMSTR : "=v"(dst) : "v"(base))
#define WAITL(NSTR) asm volatile("s_waitcnt lgkmcnt(" NSTR ")" ::: "memory")
#define SB0 __builtin_amdgcn_sched_barrier(0)

// 128x256-tile i8 MFMA GEMM (dot = Tq . Sq^T exact i32; cos = dot*QS2).
// mfma_i32_16x16x64_i8; 8 b128 + 16 MFMA per wave per 64B K-tile, staggered
// lgkm waits; 2 barriers/tile; counted vmcnt(3). Swizzle f(r)=(r>>1)&3 both
// sides. u32-key integer argmax epilogue -> per-tile partials, no atomics.
// LDS: [dbuf 2][A 128x64B | B 256x64B] = 48 KiB; 3 blocks/CU (144 KiB).
__global__ __launch_bounds__(512, 6) void k_gemm(const int8_t* __restrict__ Tq,
                                                 const int8_t* __restrict__ Sq,
                                                 u64* __restrict__ rowPart,
                                                 u64* __restrict__ colPart) {
  __shared__ __align__(16) char ldsc[49152];

  int bid = blockIdx.x;
  // XCD swizzle: NBLK3 % 8 == 0 -> chunked; consecutive swz share the A panel
  int swz = (bid & 7) * (NBLK3 / 8) + (bid >> 3);
  int rt = swz / NTN, ct = swz % NTN;
  int tileR = rt * BMT, tileC = ct * BNS;

  int tid = threadIdx.x;
  int lane = tid & 63, wid = tid >> 6;
  int wm = wid >> 2, wn = wid & 3;       // 2 x 4 wave grid; per-wave out 64x64
  int lcol = lane & 15, lrow = lane >> 4;

  const int8_t* gA = Tq + (size_t)tileR * DD;
  const int8_t* gB = Sq + (size_t)tileC * DD;

  i32x4 acc[4][4] = {};

  // LDS read bases: swizzle term (lrow ^ ((lcol>>1)&3))*16, fragment-invariant
  u32 lbase = (u32)(uintptr_t)ldsc;
  u32 swz16 = ((u32)(lrow ^ ((lcol >> 1) & 3))) << 4;
  u32 aoff0 = lbase + (u32)(wm * 64 + lcol) * 64u + swz16;
  u32 boff0 = lbase + 8192u + (u32)(wn * 64 + lcol) * 64u + swz16;
  u32 aoff1 = aoff0 + 24576u, boff1 = boff0 + 24576u;

  // stage K-tile t into dbuf db: linear LDS dest + inverse-swizzled global col
  auto STAGE = [&](int db, int t) {
    int k0 = t * 64;
    {
      int r = tid >> 2, s = tid & 3;     // A: 128x64B, 1 chunk/thread
      const int8_t* g = gA + (size_t)r * DD + k0 + ((s ^ ((r >> 1) & 3)) << 4);
      __builtin_amdgcn_global_load_lds(
          (const __attribute__((address_space(1))) void*)g,
          (__attribute__((address_space(3))) void*)(ldsc + db * 24576 + tid * 16),
          16, 0, 0);
    }
    #pragma unroll
    for (int q2 = 0; q2 < 2; ++q2) {     // B: 256x64B, 2 chunks/thread
      int ch = q2 * 512 + tid;
      int r = ch >> 2, s = ch & 3;
      const int8_t* g = gB + (size_t)r * DD + k0 + ((s ^ ((r >> 1) & 3)) << 4);
      __builtin_amdgcn_global_load_lds(
          (const __attribute__((address_space(1))) void*)g,
          (__attribute__((address_space(3))) void*)(ldsc + db * 24576 + 8192 + ch * 16),
          16, 0, 0);
    }
  };

  i32x4 a[4], b[4];
#define MM(m) do { \
    acc[m][0] = __builtin_amdgcn_mfma_i32_16x16x64_i8(a[m], b[0], acc[m][0], 0, 0, 0); \
    acc[m][1] = __builtin_amdgcn_mfma_i32_16x16x64_i8(a[m], b[1], acc[m][1], 0, 0, 0); \
    acc[m][2] = __builtin_amdgcn_mfma_i32_16x16x64_i8(a[m], b[2], acc[m][2], 0, 0, 0); \
    acc[m][3] = __builtin_amdgcn_mfma_i32_16x16x64_i8(a[m], b[3], acc[m][3], 0, 0, 0); \
  } while (0)

#define KSRUN(AOFF, BOFF) do { \
    DSR(a[0], AOFF, "0"); \
    DSR(b[0], BOFF, "0");    DSR(b[1], BOFF, "1024"); \
    DSR(b[2], BOFF, "2048"); DSR(b[3], BOFF, "3072"); \
    DSR(a[1], AOFF, "1024"); DSR(a[2], AOFF, "2048"); DSR(a[3], AOFF, "3072"); \
    __builtin_amdgcn_s_setprio(1); \
    WAITL("3"); SB0; MM(0); \
    WAITL("2"); SB0; MM(1); \
    WAITL("1"); SB0; MM(2); \
    WAITL("0"); SB0; MM(3); \
    __builtin_amdgcn_s_setprio(0); \
  } while (0)

  STAGE(0, 0);
  for (int it = 0; it < KT / 2; ++it) {
    int t1 = 2 * it + 1, t2 = 2 * it + 2;
    __builtin_amdgcn_s_barrier();        // reads of tile 2it-1 retired
    STAGE(1, t1);                        // t1 <= 15 always
    asm volatile("s_waitcnt vmcnt(3)" ::: "memory");   // tile 2it landed
    __builtin_amdgcn_s_barrier();        // visible to all waves
    KSRUN(aoff0, boff0);
    __builtin_amdgcn_s_barrier();        // reads of tile 2it retired
    if (t2 < KT) {
      STAGE(0, t2);
      asm volatile("s_waitcnt vmcnt(3)" ::: "memory");
    } else {
      asm volatile("s_waitcnt vmcnt(0)" ::: "memory");
    }
    __builtin_amdgcn_s_barrier();
    KSRUN(aoff1, boff1);
  }

  // ---- epilogue: integer-key bidirectional argmax -> per-tile partials ----
  __syncthreads();                  // full drain; LDS now reusable
  u64* rowLds = (u64*)ldsc;           // [4 wn][128 rows]  4KB
  u64* colLds = (u64*)(ldsc + 4096);  // [2 wm][256 cols]  4KB

  const u32 KB = ((u32)DBIAS) << 8;   // bias<<8
  // row best: per target row (m,lrow,j), reduce over n then lcol (16 lanes)
  u32 Cr0 = KB + 255u - (u32)(wn * 64 + lcol);
  #pragma unroll
  for (int m = 0; m < 4; ++m) {
    #pragma unroll
    for (int j = 0; j < 4; ++j) {
      u32 best = umx(umx((u32)(acc[m][0][j] << 8) + Cr0,
                         (u32)(acc[m][1][j] << 8) + (Cr0 - 16u)),
                     umx((u32)(acc[m][2][j] << 8) + (Cr0 - 32u),
                         (u32)(acc[m][3][j] << 8) + (Cr0 - 48u)));
      #pragma unroll
      for (int s = 1; s < 16; s <<= 1)
        best = umx(best, (u32)__shfl_xor((int)best, s, 64));
      if (lcol == 0) {
        u32 col = (u32)tileC + 255u - (best & 255u);
        rowLds[wn * 128 + wm * 64 + m * 16 + lrow * 4 + j] =
            ((u64)(best >> 8) << 32) | (u32)~col;
      }
    }
  }
  // col best: per source col (n,lcol), reduce over (m,j) then lrow (xor 16,32)
  u32 Cc0 = KB + 127u - (u32)(wm * 64 + lrow * 4);
  #pragma unroll
  for (int n = 0; n < 4; ++n) {
    u32 best = 0u;
    #pragma unroll
    for (int m = 0; m < 4; ++m)
      #pragma unroll
      for (int j = 0; j < 4; ++j)
        best = umx(best, (u32)(acc[m][n][j] << 8) + (Cc0 - (u32)(m * 16 + j)));
    best = umx(best, (u32)__shfl_xor((int)best, 16, 64));
    best = umx(best, (u32)__shfl_xor((int)best, 32, 64));
    if (lrow == 0) {
      u32 row = (u32)tileR + 127u - (best & 255u);
      colLds[wm * 256 + wn * 64 + n * 16 + lcol] =
          ((u64)(best >> 8) << 32) | (u32)~row;
    }
  }
  __syncthreads();
  if (tid < 128) {
    u64 b2 = rowLds[tid];
    b2 = umax(b2, rowLds[128 + tid]);
    b2 = umax(b2, rowLds[256 + tid]);
    b2 = umax(b2, rowLds[384 + tid]);
    rowPart[(size_t)ct * NPAD2 + tileR + tid] = b2;
  } else if (tid < 384) {
    int c = tid - 128;
    colPart[(size_t)rt * NPAD2 + tileC + c] = umax(colLds[c], colLds[256 + c]);
  }
#undef KSRUN
#undef MM
}

// per-n max over tile-partials (36 row / 72 col) + analytic loss -> block sums
__global__ __launch_bounds__(256) void k_redloss(const u64* __restrict__ rowPart,
                                                 const u64* __restrict__ colPart,
                                                 const float* __restrict__ sq_s,
                                                 const float* __restrict__ sq_t,
                                                 float* __restrict__ part) {
  __shared__ float r0[256], r1[256];
  int t = threadIdx.x;
  int n = blockIdx.x * 256 + t;   // grid 36 -> 9216
  float lt = 0.f, ls = 0.f;
  u64 r = 0ull, c = 0ull;
  for (int i = 0; i < NTN; ++i) {
    u64 x = rowPart[(size_t)i * NPAD2 + n]; if (x > r) r = x;
  }
  for (int i = 0; i < NTM; ++i) {
    u64 y = colPart[(size_t)i * NPAD2 + n]; if (y > c) c = y;
  }
  if (n < NP) {
    {
      float sc = (float)((int)(u32)(r >> 32) - DBIAS) * QS2;
      u32 m = ~((u32)r);
      float a = sq_t[n], cc = sq_s[m];
      lt = a + cc - 2.f * sc * (sqrtf(a) + FEPS) * (sqrtf(cc) + FEPS);
    }
    {
      float sc = (float)((int)(u32)(c >> 32) - DBIAS) * QS2;
      u32 m = ~((u32)c);
      float a = sq_s[n], cc = sq_t[m];
      ls = a + cc - 2.f * sc * (sqrtf(a) + FEPS) * (sqrtf(cc) + FEPS);
    }
  }
  r0[t] = lt; r1[t] = ls;
  __syncthreads();
  for (int s = 128; s > 0; s >>= 1) {
    if (t < s) { r0[t] += r0[t + s]; r1[t] += r1[t + s]; }
    __syncthreads();
  }
  if (t == 0) { part[blockIdx.x * 2] = r0[0]; part[blockIdx.x * 2 + 1] = r1[0]; }
}

// deterministic final sum of the 36 per-block partials
__global__ __launch_bounds__(64) void k_fin(const float* __restrict__ part,
                                            float* __restrict__ out) {
  int l = threadIdx.x;
  float lt = (l < 36) ? part[l * 2] : 0.f;
  float ls = (l < 36) ? part[l * 2 + 1] : 0.f;
  #pragma unroll
  for (int s = 1; s < 64; s <<= 1) {
    lt += __shfl_xor(lt, s, 64);
    ls += __shfl_xor(ls, s, 64);
  }
  if (l == 0) {
    const float scale = 0.5f / ((float)NP * (float)DD);
    out[0] = lt * scale;   // loss_target
    out[1] = ls * scale;   // loss_source
  }
}

extern "C" void kernel_launch(void* const* d_in, const int* in_sizes, int n_in,
                              void* d_out, int out_size, void* d_ws, size_t ws_size,
                              hipStream_t stream) {
  const float* src = (const float*)d_in[0];
  const float* tgt = (const float*)d_in[1];
  float* out = (float*)d_out;
  char* ws = (char*)d_ws;
  size_t o = 0;
  int8_t* Sq = (int8_t*)(ws + o); o += (size_t)NPAD2 * DD;
  int8_t* Tq = (int8_t*)(ws + o); o += (size_t)NPAD2 * DD;
  float* sq_s = (float*)(ws + o); o += (size_t)NPAD2 * 4;
  float* sq_t = (float*)(ws + o); o += (size_t)NPAD2 * 4;
  float* qpart = (float*)(ws + o); o += (size_t)8 * HH * WW * 4;
  u64* rowPart = (u64*)(ws + o); o += (size_t)NTN * NPAD2 * 8;
  u64* colPart = (u64*)(ws + o); o += (size_t)NTM * NPAD2 * 8;
  float* part = (float*)(ws + o); o += 1024;
  if (ws_size < o) return;  // ~27.7 MiB needed

  k_q<<<dim3(36, 4, 2), 256, 0, stream>>>(src, tgt, qpart, Sq, Tq);
  k_sq<<<36, 256, 0, stream>>>(qpart, sq_s, sq_t);
  k_norm<<<dim3(16, PH, 2), 128, 0, stream>>>(src, tgt, sq_s, sq_t, Sq, Tq);
  k_gemm<<<NBLK3, 512, 0, stream>>>(Tq, Sq, rowPart, colPart);
  k_redloss<<<36, 256, 0, stream>>>(rowPart, colPart, sq_s, sq_t, part);
  k_fin<<<1, 64, 0, stream>>>(part, out);
}

// Round 13
// 202.083 us; speedup vs baseline: 6.0235x; 6.0235x over previous
//
#include <hip/hip_runtime.h>
#include <hip/hip_bf16.h>
#include <stdint.h>

#define HH 96
#define WW 96
#define NCH 256
#define PH 95
#define PW 95
#define NP 9025          // PH*PW
#define DD 1024          // 4*NCH (bytes per row in i8)
#define FEPS 1e-8f

#define BMT 128          // target rows per block
#define BNS 256          // source cols per block
#define NTM 72           // row tiles (9216/128)
#define NTN 36           // col tiles (9216/256)
#define NPAD2 9216
#define NBLK3 2592       // NTM*NTN (divisible by 8)
#define KT 16            // DD/64
#define QSCL 508.0f
#define QS2 (1.0f / (508.0f * 508.0f))
#define DBIAS (1 << 19)  // dot bias (|dot| < 2^19)

typedef __attribute__((ext_vector_type(4))) int i32x4;
typedef __attribute__((ext_vector_type(4))) unsigned int u32x4;
typedef unsigned long long u64;
typedef unsigned int u32;
using bf16 = __hip_bfloat16;

__device__ __forceinline__ u32 umx(u32 a, u32 b) { return a > b ? a : b; }
__device__ __forceinline__ u64 umax(u64 a, u64 b) { return a > b ? a : b; }

// per-pixel partial (64-ch) sum of squares; g=blockIdx.y, img=blockIdx.z.
// Also zeroes pad rows of Sq/Tq (g==0 blocks only).
__global__ __launch_bounds__(256) void k_q(const float* __restrict__ src,
                                           const float* __restrict__ tgt,
                                           float* __restrict__ qpart,
                                           int8_t* __restrict__ Sq,
                                           int8_t* __restrict__ Tq) {
  int p = blockIdx.x * 256 + threadIdx.x;  // 36*256 == 9216 exactly
  int g = blockIdx.y;                      // channel group (4 x 64)
  const float* img = blockIdx.z ? tgt : src;
  const float* base = img + (size_t)(g * 64) * (HH * WW);
  float acc = 0.f;
  #pragma unroll 8
  for (int c = 0; c < 64; ++c) {
    float v = base[(size_t)c * (HH * WW) + p];
    acc = fmaf(v, v, acc);
  }
  qpart[((size_t)blockIdx.z * 4 + g) * (HH * WW) + p] = acc;
  if (g == 0) {  // zero pad rows NP..NPAD2 (pad dot = 0, never wins)
    const int padWords = (NPAD2 - NP) * DD / 4;  // u32 words
    u32* pw = (u32*)((blockIdx.z ? Tq : Sq) + (size_t)NP * DD);
    for (int j = p; j < padWords; j += 36 * 256) pw[j] = 0u;
  }
}

// per-patch squared norm = 4-group x 4-point sum of qpart
__global__ __launch_bounds__(256) void k_sq(const float* __restrict__ qpart,
                                            float* __restrict__ sq_s,
                                            float* __restrict__ sq_t) {
  int n = blockIdx.x * 256 + threadIdx.x;
  if (n >= NP) return;
  int y = n / PW, x = n - y * PW;
  int b = y * WW + x;
  float s = 0.f, t = 0.f;
  #pragma unroll
  for (int g = 0; g < 4; ++g) {
    const float* qs = qpart + (size_t)g * (HH * WW);
    const float* qt = qpart + (size_t)(4 + g) * (HH * WW);
    s += qs[b] + qs[b + 1] + qs[b + WW] + qs[b + WW + 1];
    t += qt[b] + qt[b + 1] + qt[b + WW] + qt[b + WW + 1];
  }
  sq_s[n] = s; sq_t[n] = t;
}

// normalized, globally-scaled i8 patch matrix [NPAD2][DD] via LDS transpose.
// Coalesced output: each thread packs 16 i8 -> one dwordx4 store.
// z = 0: (src, sq_s) -> Sq ; z = 1: (tgt, sq_t) -> Tq
__global__ __launch_bounds__(128) void k_norm(const float* __restrict__ src,
                                              const float* __restrict__ tgt,
                                              const float* __restrict__ sq_s,
                                              const float* __restrict__ sq_t,
                                              int8_t* __restrict__ Sq,
                                              int8_t* __restrict__ Tq) {
  __shared__ float tile[64 * 129];
  __shared__ float rn[PW];
  const float* img = blockIdx.z ? tgt : src;
  const float* sq = blockIdx.z ? sq_t : sq_s;
  int8_t* out = blockIdx.z ? Tq : Sq;
  int y = blockIdx.y;
  int d0 = blockIdx.x * 64;     // 16 chunks of 64 d's
  int k = d0 >> 8;              // which 2x2 shift
  int c0 = d0 & 255;
  int iy = k >> 1, jx = k & 1;
  int t = threadIdx.x;
  if (t < PW) rn[t] = QSCL / (sqrtf(sq[y * PW + t]) + FEPS);
  int x = t;
  const float* base = img + (size_t)(y + iy) * WW + jx;
  #pragma unroll 4
  for (int dl = 0; dl < 64; ++dl) {
    int c = c0 + dl;
    float v = (x < PW) ? base[(size_t)c * (HH * WW) + x] : 0.f;
    tile[dl * 129 + x] = v;
  }
  __syncthreads();
  int part = t & 3;             // 16 d's per part
  int xl0 = t >> 2;             // 32 xl per pass
  #pragma unroll
  for (int pass = 0; pass < 3; ++pass) {
    int xl = xl0 + pass * 32;
    if (xl < PW) {
      float r = rn[xl];
      u32x4 w;
      #pragma unroll
      for (int g = 0; g < 4; ++g) {
        u32 pk = 0;
        #pragma unroll
        for (int bb = 0; bb < 4; ++bb) {
          int dl = part * 16 + g * 4 + bb;
          float qv = tile[dl * 129 + xl] * r;
          qv = fminf(fmaxf(qv, -127.f), 127.f);
          pk |= ((u32)(uint8_t)(int8_t)(int)rintf(qv)) << (8 * bb);
        }
        w[g] = pk;
      }
      *(u32x4*)(out + (size_t)(y * PW + xl) * DD + d0 + part * 16) = w;
    }
  }
}

// ---- inline-asm helpers ----
#define DSR(dst, base, IMMSTR) \
  asm volatile("ds_read_b128 %0, %1 offset:" IMMSTR : "=v"(dst) : "v"(base))
#define WAITL(NSTR) asm volatile("s_waitcnt lgkmcnt(" NSTR ")" ::: "memory")
#define SB0 __builtin_amdgcn_sched_barrier(0)

// 128x256-tile i8 MFMA GEMM (dot = Tq . Sq^T exact i32; cos = dot*QS2).
// mfma_i32_16x16x64_i8; 8 b128 + 16 MFMA per wave per 64B K-tile, staggered
// lgkm waits; 2 barriers/tile; counted vmcnt(3). Swizzle f(r)=(r>>1)&3 both
// sides. u32-key integer argmax epilogue -> per-tile partials, no atomics.
// LDS: [dbuf 2][A 128x64B | B 256x64B] = 48 KiB; 2 blocks/CU.
// NOTE: (512,4) is the register-feasibility limit: ~128 regs/wave (64 VGPR +
// 64 acc) x 4 waves/EU = full pool. (512,6) forces 40 VGPR -> scratch spill
// disaster (R12: 10x regression). Do not raise.
__global__ __launch_bounds__(512, 4) void k_gemm(const int8_t* __restrict__ Tq,
                                                 const int8_t* __restrict__ Sq,
                                                 u64* __restrict__ rowPart,
                                                 u64* __restrict__ colPart) {
  __shared__ __align__(16) char ldsc[49152];

  int bid = blockIdx.x;
  // XCD swizzle: NBLK3 % 8 == 0 -> chunked; consecutive swz share the A panel
  int swz = (bid & 7) * (NBLK3 / 8) + (bid >> 3);
  int rt = swz / NTN, ct = swz % NTN;
  int tileR = rt * BMT, tileC = ct * BNS;

  int tid = threadIdx.x;
  int lane = tid & 63, wid = tid >> 6;
  int wm = wid >> 2, wn = wid & 3;       // 2 x 4 wave grid; per-wave out 64x64
  int lcol = lane & 15, lrow = lane >> 4;

  const int8_t* gA = Tq + (size_t)tileR * DD;
  const int8_t* gB = Sq + (size_t)tileC * DD;

  i32x4 acc[4][4] = {};

  // LDS read bases: swizzle term (lrow ^ ((lcol>>1)&3))*16, fragment-invariant
  u32 lbase = (u32)(uintptr_t)ldsc;
  u32 swz16 = ((u32)(lrow ^ ((lcol >> 1) & 3))) << 4;
  u32 aoff0 = lbase + (u32)(wm * 64 + lcol) * 64u + swz16;
  u32 boff0 = lbase + 8192u + (u32)(wn * 64 + lcol) * 64u + swz16;
  u32 aoff1 = aoff0 + 24576u, boff1 = boff0 + 24576u;

  // stage K-tile t into dbuf db: linear LDS dest + inverse-swizzled global col
  auto STAGE = [&](int db, int t) {
    int k0 = t * 64;
    {
      int r = tid >> 2, s = tid & 3;     // A: 128x64B, 1 chunk/thread
      const int8_t* g = gA + (size_t)r * DD + k0 + ((s ^ ((r >> 1) & 3)) << 4);
      __builtin_amdgcn_global_load_lds(
          (const __attribute__((address_space(1))) void*)g,
          (__attribute__((address_space(3))) void*)(ldsc + db * 24576 + tid * 16),
          16, 0, 0);
    }
    #pragma unroll
    for (int q2 = 0; q2 < 2; ++q2) {     // B: 256x64B, 2 chunks/thread
      int ch = q2 * 512 + tid;
      int r = ch >> 2, s = ch & 3;
      const int8_t* g = gB + (size_t)r * DD + k0 + ((s ^ ((r >> 1) & 3)) << 4);
      __builtin_amdgcn_global_load_lds(
          (const __attribute__((address_space(1))) void*)g,
          (__attribute__((address_space(3))) void*)(ldsc + db * 24576 + 8192 + ch * 16),
          16, 0, 0);
    }
  };

  i32x4 a[4], b[4];
#define MM(m) do { \
    acc[m][0] = __builtin_amdgcn_mfma_i32_16x16x64_i8(a[m], b[0], acc[m][0], 0, 0, 0); \
    acc[m][1] = __builtin_amdgcn_mfma_i32_16x16x64_i8(a[m], b[1], acc[m][1], 0, 0, 0); \
    acc[m][2] = __builtin_amdgcn_mfma_i32_16x16x64_i8(a[m], b[2], acc[m][2], 0, 0, 0); \
    acc[m][3] = __builtin_amdgcn_mfma_i32_16x16x64_i8(a[m], b[3], acc[m][3], 0, 0, 0); \
  } while (0)

#define KSRUN(AOFF, BOFF) do { \
    DSR(a[0], AOFF, "0"); \
    DSR(b[0], BOFF, "0");    DSR(b[1], BOFF, "1024"); \
    DSR(b[2], BOFF, "2048"); DSR(b[3], BOFF, "3072"); \
    DSR(a[1], AOFF, "1024"); DSR(a[2], AOFF, "2048"); DSR(a[3], AOFF, "3072"); \
    __builtin_amdgcn_s_setprio(1); \
    WAITL("3"); SB0; MM(0); \
    WAITL("2"); SB0; MM(1); \
    WAITL("1"); SB0; MM(2); \
    WAITL("0"); SB0; MM(3); \
    __builtin_amdgcn_s_setprio(0); \
  } while (0)

  STAGE(0, 0);
  for (int it = 0; it < KT / 2; ++it) {
    int t1 = 2 * it + 1, t2 = 2 * it + 2;
    __builtin_amdgcn_s_barrier();        // reads of tile 2it-1 retired
    STAGE(1, t1);                        // t1 <= 15 always
    asm volatile("s_waitcnt vmcnt(3)" ::: "memory");   // tile 2it landed
    __builtin_amdgcn_s_barrier();        // visible to all waves
    KSRUN(aoff0, boff0);
    __builtin_amdgcn_s_barrier();        // reads of tile 2it retired
    if (t2 < KT) {
      STAGE(0, t2);
      asm volatile("s_waitcnt vmcnt(3)" ::: "memory");
    } else {
      asm volatile("s_waitcnt vmcnt(0)" ::: "memory");
    }
    __builtin_amdgcn_s_barrier();
    KSRUN(aoff1, boff1);
  }

  // ---- epilogue: integer-key bidirectional argmax -> per-tile partials ----
  __syncthreads();                  // full drain; LDS now reusable
  u64* rowLds = (u64*)ldsc;           // [4 wn][128 rows]  4KB
  u64* colLds = (u64*)(ldsc + 4096);  // [2 wm][256 cols]  4KB

  const u32 KB = ((u32)DBIAS) << 8;   // bias<<8
  // row best: per target row (m,lrow,j), reduce over n then lcol (16 lanes)
  u32 Cr0 = KB + 255u - (u32)(wn * 64 + lcol);
  #pragma unroll
  for (int m = 0; m < 4; ++m) {
    #pragma unroll
    for (int j = 0; j < 4; ++j) {
      u32 best = umx(umx((u32)(acc[m][0][j] << 8) + Cr0,
                         (u32)(acc[m][1][j] << 8) + (Cr0 - 16u)),
                     umx((u32)(acc[m][2][j] << 8) + (Cr0 - 32u),
                         (u32)(acc[m][3][j] << 8) + (Cr0 - 48u)));
      #pragma unroll
      for (int s = 1; s < 16; s <<= 1)
        best = umx(best, (u32)__shfl_xor((int)best, s, 64));
      if (lcol == 0) {
        u32 col = (u32)tileC + 255u - (best & 255u);
        rowLds[wn * 128 + wm * 64 + m * 16 + lrow * 4 + j] =
            ((u64)(best >> 8) << 32) | (u32)~col;
      }
    }
  }
  // col best: per source col (n,lcol), reduce over (m,j) then lrow (xor 16,32)
  u32 Cc0 = KB + 127u - (u32)(wm * 64 + lrow * 4);
  #pragma unroll
  for (int n = 0; n < 4; ++n) {
    u32 best = 0u;
    #pragma unroll
    for (int m = 0; m < 4; ++m)
      #pragma unroll
      for (int j = 0; j < 4; ++j)
        best = umx(best, (u32)(acc[m][n][j] << 8) + (Cc0 - (u32)(m * 16 + j)));
    best = umx(best, (u32)__shfl_xor((int)best, 16, 64));
    best = umx(best, (u32)__shfl_xor((int)best, 32, 64));
    if (lrow == 0) {
      u32 row = (u32)tileR + 127u - (best & 255u);
      colLds[wm * 256 + wn * 64 + n * 16 + lcol] =
          ((u64)(best >> 8) << 32) | (u32)~row;
    }
  }
  __syncthreads();
  if (tid < 128) {
    u64 b2 = rowLds[tid];
    b2 = umax(b2, rowLds[128 + tid]);
    b2 = umax(b2, rowLds[256 + tid]);
    b2 = umax(b2, rowLds[384 + tid]);
    rowPart[(size_t)ct * NPAD2 + tileR + tid] = b2;
  } else if (tid < 384) {
    int c = tid - 128;
    colPart[(size_t)rt * NPAD2 + tileC + c] = umax(colLds[c], colLds[256 + c]);
  }
#undef KSRUN
#undef MM
}

// per-n max over tile-partials (36 row / 72 col) + analytic loss -> block sums
__global__ __launch_bounds__(256) void k_redloss(const u64* __restrict__ rowPart,
                                                 const u64* __restrict__ colPart,
                                                 const float* __restrict__ sq_s,
                                                 const float* __restrict__ sq_t,
                                                 float* __restrict__ part) {
  __shared__ float r0[256], r1[256];
  int t = threadIdx.x;
  int n = blockIdx.x * 256 + t;   // grid 36 -> 9216
  float lt = 0.f, ls = 0.f;
  u64 r = 0ull, c = 0ull;
  for (int i = 0; i < NTN; ++i) {
    u64 x = rowPart[(size_t)i * NPAD2 + n]; if (x > r) r = x;
  }
  for (int i = 0; i < NTM; ++i) {
    u64 y = colPart[(size_t)i * NPAD2 + n]; if (y > c) c = y;
  }
  if (n < NP) {
    {
      float sc = (float)((int)(u32)(r >> 32) - DBIAS) * QS2;
      u32 m = ~((u32)r);
      float a = sq_t[n], cc = sq_s[m];
      lt = a + cc - 2.f * sc * (sqrtf(a) + FEPS) * (sqrtf(cc) + FEPS);
    }
    {
      float sc = (float)((int)(u32)(c >> 32) - DBIAS) * QS2;
      u32 m = ~((u32)c);
      float a = sq_s[n], cc = sq_t[m];
      ls = a + cc - 2.f * sc * (sqrtf(a) + FEPS) * (sqrtf(cc) + FEPS);
    }
  }
  r0[t] = lt; r1[t] = ls;
  __syncthreads();
  for (int s = 128; s > 0; s >>= 1) {
    if (t < s) { r0[t] += r0[t + s]; r1[t] += r1[t + s]; }
    __syncthreads();
  }
  if (t == 0) { part[blockIdx.x * 2] = r0[0]; part[blockIdx.x * 2 + 1] = r1[0]; }
}

// deterministic final sum of the 36 per-block partials
__global__ __launch_bounds__(64) void k_fin(const float* __restrict__ part,
                                            float* __restrict__ out) {
  int l = threadIdx.x;
  float lt = (l < 36) ? part[l * 2] : 0.f;
  float ls = (l < 36) ? part[l * 2 + 1] : 0.f;
  #pragma unroll
  for (int s = 1; s < 64; s <<= 1) {
    lt += __shfl_xor(lt, s, 64);
    ls += __shfl_xor(ls, s, 64);
  }
  if (l == 0) {
    const float scale = 0.5f / ((float)NP * (float)DD);
    out[0] = lt * scale;   // loss_target
    out[1] = ls * scale;   // loss_source
  }
}

extern "C" void kernel_launch(void* const* d_in, const int* in_sizes, int n_in,
                              void* d_out, int out_size, void* d_ws, size_t ws_size,
                              hipStream_t stream) {
  const float* src = (const float*)d_in[0];
  const float* tgt = (const float*)d_in[1];
  float* out = (float*)d_out;
  char* ws = (char*)d_ws;
  size_t o = 0;
  int8_t* Sq = (int8_t*)(ws + o); o += (size_t)NPAD2 * DD;
  int8_t* Tq = (int8_t*)(ws + o); o += (size_t)NPAD2 * DD;
  float* sq_s = (float*)(ws + o); o += (size_t)NPAD2 * 4;
  float* sq_t = (float*)(ws + o); o += (size_t)NPAD2 * 4;
  float* qpart = (float*)(ws + o); o += (size_t)8 * HH * WW * 4;
  u64* rowPart = (u64*)(ws + o); o += (size_t)NTN * NPAD2 * 8;
  u64* colPart = (u64*)(ws + o); o += (size_t)NTM * NPAD2 * 8;
  float* part = (float*)(ws + o); o += 1024;
  if (ws_size < o) return;  // ~27.7 MiB needed

  k_q<<<dim3(36, 4, 2), 256, 0, stream>>>(src, tgt, qpart, Sq, Tq);
  k_sq<<<36, 256, 0, stream>>>(qpart, sq_s, sq_t);
  k_norm<<<dim3(16, PH, 2), 128, 0, stream>>>(src, tgt, sq_s, sq_t, Sq, Tq);
  k_gemm<<<NBLK3, 512, 0, stream>>>(Tq, Sq, rowPart, colPart);
  k_redloss<<<36, 256, 0, stream>>>(rowPart, colPart, sq_s, sq_t, part);
  k_fin<<<1, 64, 0, stream>>>(part, out);
}

// Round 14
// 202.050 us; speedup vs baseline: 6.0244x; 1.0002x over previous
//
#include <hip/hip_runtime.h>
#include <hip/hip_bf16.h>
#include <stdint.h>

#define HH 96
#define WW 96
#define NCH 256
#define PH 95
#define PW 95
#define NP 9025          // PH*PW
#define DD 1024          // 4*NCH (bytes per row in i8)
#define FEPS 1e-8f

#define BMT 128          // target rows per block
#define BNS 256          // source cols per block
#define NTM 72           // row tiles (9216/128)
#define NTN 36           // col tiles (9216/256)
#define NPAD2 9216
#define NBLK3 2592       // NTM*NTN (divisible by 8)
#define KT 16            // DD/64
#define QSCL 508.0f
#define QS2 (1.0f / (508.0f * 508.0f))
#define DBIAS (1 << 19)  // dot bias (|dot| < 2^19)

typedef __attribute__((ext_vector_type(4))) int i32x4;
typedef __attribute__((ext_vector_type(4))) unsigned int u32x4;
typedef unsigned long long u64;
typedef unsigned int u32;
using bf16 = __hip_bfloat16;

__device__ __forceinline__ u32 umx(u32 a, u32 b) { return a > b ? a : b; }
__device__ __forceinline__ u64 umax(u64 a, u64 b) { return a > b ? a : b; }

// per-pixel partial (64-ch) sum of squares; g=blockIdx.y, img=blockIdx.z.
// Also zeroes pad rows of Sq/Tq (g==0 blocks) and the redloss counter.
__global__ __launch_bounds__(256) void k_q(const float* __restrict__ src,
                                           const float* __restrict__ tgt,
                                           float* __restrict__ qpart,
                                           int8_t* __restrict__ Sq,
                                           int8_t* __restrict__ Tq,
                                           u32* __restrict__ ctr) {
  int p = blockIdx.x * 256 + threadIdx.x;  // 36*256 == 9216 exactly
  int g = blockIdx.y;                      // channel group (4 x 64)
  const float* img = blockIdx.z ? tgt : src;
  const float* base = img + (size_t)(g * 64) * (HH * WW);
  float acc = 0.f;
  #pragma unroll 8
  for (int c = 0; c < 64; ++c) {
    float v = base[(size_t)c * (HH * WW) + p];
    acc = fmaf(v, v, acc);
  }
  qpart[((size_t)blockIdx.z * 4 + g) * (HH * WW) + p] = acc;
  if (g == 0) {  // zero pad rows NP..NPAD2 (pad dot = 0, never wins)
    const int padWords = (NPAD2 - NP) * DD / 4;  // u32 words
    u32* pw = (u32*)((blockIdx.z ? Tq : Sq) + (size_t)NP * DD);
    for (int j = p; j < padWords; j += 36 * 256) pw[j] = 0u;
  }
  if (p == 0 && g == 0 && blockIdx.z == 0) *ctr = 0u;
}

// per-patch squared norm = 4-group x 4-point sum of qpart
__global__ __launch_bounds__(256) void k_sq(const float* __restrict__ qpart,
                                            float* __restrict__ sq_s,
                                            float* __restrict__ sq_t) {
  int n = blockIdx.x * 256 + threadIdx.x;
  if (n >= NP) return;
  int y = n / PW, x = n - y * PW;
  int b = y * WW + x;
  float s = 0.f, t = 0.f;
  #pragma unroll
  for (int g = 0; g < 4; ++g) {
    const float* qs = qpart + (size_t)g * (HH * WW);
    const float* qt = qpart + (size_t)(4 + g) * (HH * WW);
    s += qs[b] + qs[b + 1] + qs[b + WW] + qs[b + WW + 1];
    t += qt[b] + qt[b + 1] + qt[b + WW] + qt[b + WW + 1];
  }
  sq_s[n] = s; sq_t[n] = t;
}

// normalized, globally-scaled i8 patch matrix [NPAD2][DD] via LDS transpose.
// Coalesced output: each thread packs 16 i8 -> one dwordx4 store.
// z = 0: (src, sq_s) -> Sq ; z = 1: (tgt, sq_t) -> Tq
__global__ __launch_bounds__(128) void k_norm(const float* __restrict__ src,
                                              const float* __restrict__ tgt,
                                              const float* __restrict__ sq_s,
                                              const float* __restrict__ sq_t,
                                              int8_t* __restrict__ Sq,
                                              int8_t* __restrict__ Tq) {
  __shared__ float tile[64 * 129];
  __shared__ float rn[PW];
  const float* img = blockIdx.z ? tgt : src;
  const float* sq = blockIdx.z ? sq_t : sq_s;
  int8_t* out = blockIdx.z ? Tq : Sq;
  int y = blockIdx.y;
  int d0 = blockIdx.x * 64;     // 16 chunks of 64 d's
  int k = d0 >> 8;              // which 2x2 shift
  int c0 = d0 & 255;
  int iy = k >> 1, jx = k & 1;
  int t = threadIdx.x;
  if (t < PW) rn[t] = QSCL / (sqrtf(sq[y * PW + t]) + FEPS);
  int x = t;
  const float* base = img + (size_t)(y + iy) * WW + jx;
  #pragma unroll 4
  for (int dl = 0; dl < 64; ++dl) {
    int c = c0 + dl;
    float v = (x < PW) ? base[(size_t)c * (HH * WW) + x] : 0.f;
    tile[dl * 129 + x] = v;
  }
  __syncthreads();
  int part = t & 3;             // 16 d's per part
  int xl0 = t >> 2;             // 32 xl per pass
  #pragma unroll
  for (int pass = 0; pass < 3; ++pass) {
    int xl = xl0 + pass * 32;
    if (xl < PW) {
      float r = rn[xl];
      u32x4 w;
      #pragma unroll
      for (int g = 0; g < 4; ++g) {
        u32 pk = 0;
        #pragma unroll
        for (int bb = 0; bb < 4; ++bb) {
          int dl = part * 16 + g * 4 + bb;
          float qv = tile[dl * 129 + xl] * r;
          qv = fminf(fmaxf(qv, -127.f), 127.f);
          pk |= ((u32)(uint8_t)(int8_t)(int)rintf(qv)) << (8 * bb);
        }
        w[g] = pk;
      }
      *(u32x4*)(out + (size_t)(y * PW + xl) * DD + d0 + part * 16) = w;
    }
  }
}

// ---- inline-asm helpers ----
#define DSR(dst, base, IMMSTR) \
  asm volatile("ds_read_b128 %0, %1 offset:" IMMSTR : "=v"(dst) : "v"(base))
#define WAITL(NSTR) asm volatile("s_waitcnt lgkmcnt(" NSTR ")" ::: "memory")
#define SB0 __builtin_amdgcn_sched_barrier(0)

// 128x256-tile i8 MFMA GEMM (dot = Tq . Sq^T exact i32; cos = dot*QS2).
// mfma_i32_16x16x64_i8; 8 b128 + 16 MFMA per wave per 64B K-tile, staggered
// lgkm waits. 3-BUFFER RING, prefetch distance 2: tile t's loads issued two
// tile-sections ahead -> vmcnt(6) wait is off the latency critical path.
// 2 barriers/tile. Swizzle f(r)=(r>>1)&3 both sides. u32-key integer argmax
// epilogue -> per-tile partials, no atomics.
// LDS: 3 x [A 128x64B | B 256x64B] = 72 KiB; 2 blocks/CU.
// NOTE: (512,4) is the register-feasibility limit: ~128 regs/wave (64 VGPR +
// 64 acc) x 4 waves/EU = full pool. (512,6) forces 40 VGPR -> scratch spill
// disaster (R12: 10x regression). Do not raise.
__global__ __launch_bounds__(512, 4) void k_gemm(const int8_t* __restrict__ Tq,
                                                 const int8_t* __restrict__ Sq,
                                                 u64* __restrict__ rowPart,
                                                 u64* __restrict__ colPart) {
  __shared__ __align__(16) char ldsc[73728];   // 3 x 24 KiB

  int bid = blockIdx.x;
  // XCD swizzle: NBLK3 % 8 == 0 -> chunked; consecutive swz share the A panel
  int swz = (bid & 7) * (NBLK3 / 8) + (bid >> 3);
  int rt = swz / NTN, ct = swz % NTN;
  int tileR = rt * BMT, tileC = ct * BNS;

  int tid = threadIdx.x;
  int lane = tid & 63, wid = tid >> 6;
  int wm = wid >> 2, wn = wid & 3;       // 2 x 4 wave grid; per-wave out 64x64
  int lcol = lane & 15, lrow = lane >> 4;

  const int8_t* gA = Tq + (size_t)tileR * DD;
  const int8_t* gB = Sq + (size_t)tileC * DD;

  i32x4 acc[4][4] = {};

  // LDS read bases: swizzle term (lrow ^ ((lcol>>1)&3))*16, fragment-invariant
  u32 lbase = (u32)(uintptr_t)ldsc;
  u32 swz16 = ((u32)(lrow ^ ((lcol >> 1) & 3))) << 4;
  u32 aoff0 = lbase + (u32)(wm * 64 + lcol) * 64u + swz16;
  u32 boff0 = lbase + 8192u + (u32)(wn * 64 + lcol) * 64u + swz16;
  u32 aoff1 = aoff0 + 24576u, boff1 = boff0 + 24576u;
  u32 aoff2 = aoff0 + 49152u, boff2 = boff0 + 49152u;

  // stage K-tile t into ring buffer db: linear LDS dest + inverse-swizzled
  // global source column (involution).
  auto STAGE = [&](int db, int t) {
    int k0 = t * 64;
    {
      int r = tid >> 2, s = tid & 3;     // A: 128x64B, 1 chunk/thread
      const int8_t* g = gA + (size_t)r * DD + k0 + ((s ^ ((r >> 1) & 3)) << 4);
      __builtin_amdgcn_global_load_lds(
          (const __attribute__((address_space(1))) void*)g,
          (__attribute__((address_space(3))) void*)(ldsc + db * 24576 + tid * 16),
          16, 0, 0);
    }
    #pragma unroll
    for (int q2 = 0; q2 < 2; ++q2) {     // B: 256x64B, 2 chunks/thread
      int ch = q2 * 512 + tid;
      int r = ch >> 2, s = ch & 3;
      const int8_t* g = gB + (size_t)r * DD + k0 + ((s ^ ((r >> 1) & 3)) << 4);
      __builtin_amdgcn_global_load_lds(
          (const __attribute__((address_space(1))) void*)g,
          (__attribute__((address_space(3))) void*)(ldsc + db * 24576 + 8192 + ch * 16),
          16, 0, 0);
    }
  };

  i32x4 a[4], b[4];
#define MM(m) do { \
    acc[m][0] = __builtin_amdgcn_mfma_i32_16x16x64_i8(a[m], b[0], acc[m][0], 0, 0, 0); \
    acc[m][1] = __builtin_amdgcn_mfma_i32_16x16x64_i8(a[m], b[1], acc[m][1], 0, 0, 0); \
    acc[m][2] = __builtin_amdgcn_mfma_i32_16x16x64_i8(a[m], b[2], acc[m][2], 0, 0, 0); \
    acc[m][3] = __builtin_amdgcn_mfma_i32_16x16x64_i8(a[m], b[3], acc[m][3], 0, 0, 0); \
  } while (0)

#define KSRUN(AOFF, BOFF) do { \
    DSR(a[0], AOFF, "0"); \
    DSR(b[0], BOFF, "0");    DSR(b[1], BOFF, "1024"); \
    DSR(b[2], BOFF, "2048"); DSR(b[3], BOFF, "3072"); \
    DSR(a[1], AOFF, "1024"); DSR(a[2], AOFF, "2048"); DSR(a[3], AOFF, "3072"); \
    __builtin_amdgcn_s_setprio(1); \
    WAITL("3"); SB0; MM(0); \
    WAITL("2"); SB0; MM(1); \
    WAITL("1"); SB0; MM(2); \
    WAITL("0"); SB0; MM(3); \
    __builtin_amdgcn_s_setprio(0); \
  } while (0)

  // prologue: stage tiles 0,1 (distance-2 ring primed)
  STAGE(0, 0);
  STAGE(1, 1);
  // groups of 3 tiles: positions use compile-time ring indices
  // (tile 3i->buf0 stages 3i+2->buf2; 3i+1->buf1 stages 3i+3->buf0;
  //  3i+2->buf2 stages 3i+4->buf1); tiles 0..14 in-loop, tile 15 tail.
  for (int i = 0; i < 5; ++i) {
    __builtin_amdgcn_s_barrier();        // all waves done reading buf2 (t-1)
    STAGE(2, 3 * i + 2);
    asm volatile("s_waitcnt vmcnt(6)" ::: "memory");   // tile 3i landed
    __builtin_amdgcn_s_barrier();
    KSRUN(aoff0, boff0);
    __builtin_amdgcn_s_barrier();
    STAGE(0, 3 * i + 3);
    asm volatile("s_waitcnt vmcnt(6)" ::: "memory");   // tile 3i+1 landed
    __builtin_amdgcn_s_barrier();
    KSRUN(aoff1, boff1);
    __builtin_amdgcn_s_barrier();
    if (i < 4) {
      STAGE(1, 3 * i + 4);
      asm volatile("s_waitcnt vmcnt(6)" ::: "memory"); // tile 3i+2 landed
    } else {
      asm volatile("s_waitcnt vmcnt(3)" ::: "memory"); // tile 14 landed
    }
    __builtin_amdgcn_s_barrier();
    KSRUN(aoff2, boff2);
  }
  __builtin_amdgcn_s_barrier();
  asm volatile("s_waitcnt vmcnt(0)" ::: "memory");     // tile 15 landed
  __builtin_amdgcn_s_barrier();
  KSRUN(aoff0, boff0);                   // tile 15 (15%3==0 -> buf0)

  // ---- epilogue: integer-key bidirectional argmax -> per-tile partials ----
  __syncthreads();                  // full drain; LDS now reusable
  u64* rowLds = (u64*)ldsc;           // [4 wn][128 rows]  4KB
  u64* colLds = (u64*)(ldsc + 4096);  // [2 wm][256 cols]  4KB

  const u32 KB = ((u32)DBIAS) << 8;   // bias<<8
  // row best: per target row (m,lrow,j), reduce over n then lcol (16 lanes)
  u32 Cr0 = KB + 255u - (u32)(wn * 64 + lcol);
  #pragma unroll
  for (int m = 0; m < 4; ++m) {
    #pragma unroll
    for (int j = 0; j < 4; ++j) {
      u32 best = umx(umx((u32)(acc[m][0][j] << 8) + Cr0,
                         (u32)(acc[m][1][j] << 8) + (Cr0 - 16u)),
                     umx((u32)(acc[m][2][j] << 8) + (Cr0 - 32u),
                         (u32)(acc[m][3][j] << 8) + (Cr0 - 48u)));
      #pragma unroll
      for (int s = 1; s < 16; s <<= 1)
        best = umx(best, (u32)__shfl_xor((int)best, s, 64));
      if (lcol == 0) {
        u32 col = (u32)tileC + 255u - (best & 255u);
        rowLds[wn * 128 + wm * 64 + m * 16 + lrow * 4 + j] =
            ((u64)(best >> 8) << 32) | (u32)~col;
      }
    }
  }
  // col best: per source col (n,lcol), reduce over (m,j) then lrow (xor 16,32)
  u32 Cc0 = KB + 127u - (u32)(wm * 64 + lrow * 4);
  #pragma unroll
  for (int n = 0; n < 4; ++n) {
    u32 best = 0u;
    #pragma unroll
    for (int m = 0; m < 4; ++m)
      #pragma unroll
      for (int j = 0; j < 4; ++j)
        best = umx(best, (u32)(acc[m][n][j] << 8) + (Cc0 - (u32)(m * 16 + j)));
    best = umx(best, (u32)__shfl_xor((int)best, 16, 64));
    best = umx(best, (u32)__shfl_xor((int)best, 32, 64));
    if (lrow == 0) {
      u32 row = (u32)tileR + 127u - (best & 255u);
      colLds[wm * 256 + wn * 64 + n * 16 + lcol] =
          ((u64)(best >> 8) << 32) | (u32)~row;
    }
  }
  __syncthreads();
  if (tid < 128) {
    u64 b2 = rowLds[tid];
    b2 = umax(b2, rowLds[128 + tid]);
    b2 = umax(b2, rowLds[256 + tid]);
    b2 = umax(b2, rowLds[384 + tid]);
    rowPart[(size_t)ct * NPAD2 + tileR + tid] = b2;
  } else if (tid < 384) {
    int c = tid - 128;
    colPart[(size_t)rt * NPAD2 + tileC + c] = umax(colLds[c], colLds[256 + c]);
  }
#undef KSRUN
#undef MM
}

// per-n max over tile-partials (36 row / 72 col) + analytic loss -> block
// sums; the LAST block (device atomic counter) sums the 36 partials in fixed
// order (deterministic) and writes the final two losses.
__global__ __launch_bounds__(256) void k_redloss(const u64* __restrict__ rowPart,
                                                 const u64* __restrict__ colPart,
                                                 const float* __restrict__ sq_s,
                                                 const float* __restrict__ sq_t,
                                                 float* __restrict__ part,
                                                 u32* __restrict__ ctr,
                                                 float* __restrict__ out) {
  __shared__ float r0[256], r1[256];
  __shared__ int lastFlag;
  int t = threadIdx.x;
  int n = blockIdx.x * 256 + t;   // grid 36 -> 9216
  float lt = 0.f, ls = 0.f;
  u64 r = 0ull, c = 0ull;
  for (int i = 0; i < NTN; ++i) {
    u64 x = rowPart[(size_t)i * NPAD2 + n]; if (x > r) r = x;
  }
  for (int i = 0; i < NTM; ++i) {
    u64 y = colPart[(size_t)i * NPAD2 + n]; if (y > c) c = y;
  }
  if (n < NP) {
    {
      float sc = (float)((int)(u32)(r >> 32) - DBIAS) * QS2;
      u32 m = ~((u32)r);
      float a = sq_t[n], cc = sq_s[m];
      lt = a + cc - 2.f * sc * (sqrtf(a) + FEPS) * (sqrtf(cc) + FEPS);
    }
    {
      float sc = (float)((int)(u32)(c >> 32) - DBIAS) * QS2;
      u32 m = ~((u32)c);
      float a = sq_s[n], cc = sq_t[m];
      ls = a + cc - 2.f * sc * (sqrtf(a) + FEPS) * (sqrtf(cc) + FEPS);
    }
  }
  r0[t] = lt; r1[t] = ls;
  __syncthreads();
  for (int s = 128; s > 0; s >>= 1) {
    if (t < s) { r0[t] += r0[t + s]; r1[t] += r1[t + s]; }
    __syncthreads();
  }
  if (t == 0) {
    part[blockIdx.x * 2] = r0[0];
    part[blockIdx.x * 2 + 1] = r1[0];
    __threadfence();
    u32 o = atomicAdd(ctr, 1u);          // device-scope
    lastFlag = (o == 35u) ? 1 : 0;
  }
  __syncthreads();
  if (lastFlag && t < 64) {
    // last block: all other parts visible (their threadfence precedes our
    // acquire); L1-bypassing agent-scope loads, fixed summation order.
    float flt = 0.f, fls = 0.f;
    if (t < 36) {
      flt = __hip_atomic_load(&part[t * 2], __ATOMIC_RELAXED,
                              __HIP_MEMORY_SCOPE_AGENT);
      fls = __hip_atomic_load(&part[t * 2 + 1], __ATOMIC_RELAXED,
                              __HIP_MEMORY_SCOPE_AGENT);
    }
    #pragma unroll
    for (int s = 1; s < 64; s <<= 1) {
      flt += __shfl_xor(flt, s, 64);
      fls += __shfl_xor(fls, s, 64);
    }
    if (t == 0) {
      const float scale = 0.5f / ((float)NP * (float)DD);
      out[0] = flt * scale;   // loss_target
      out[1] = fls * scale;   // loss_source
    }
  }
}

extern "C" void kernel_launch(void* const* d_in, const int* in_sizes, int n_in,
                              void* d_out, int out_size, void* d_ws, size_t ws_size,
                              hipStream_t stream) {
  const float* src = (const float*)d_in[0];
  const float* tgt = (const float*)d_in[1];
  float* out = (float*)d_out;
  char* ws = (char*)d_ws;
  size_t o = 0;
  int8_t* Sq = (int8_t*)(ws + o); o += (size_t)NPAD2 * DD;
  int8_t* Tq = (int8_t*)(ws + o); o += (size_t)NPAD2 * DD;
  float* sq_s = (float*)(ws + o); o += (size_t)NPAD2 * 4;
  float* sq_t = (float*)(ws + o); o += (size_t)NPAD2 * 4;
  float* qpart = (float*)(ws + o); o += (size_t)8 * HH * WW * 4;
  u64* rowPart = (u64*)(ws + o); o += (size_t)NTN * NPAD2 * 8;
  u64* colPart = (u64*)(ws + o); o += (size_t)NTM * NPAD2 * 8;
  float* part = (float*)(ws + o); o += 512;
  u32* ctr = (u32*)(ws + o); o += 64;
  if (ws_size < o) return;  // ~27.7 MiB needed

  k_q<<<dim3(36, 4, 2), 256, 0, stream>>>(src, tgt, qpart, Sq, Tq, ctr);
  k_sq<<<36, 256, 0, stream>>>(qpart, sq_s, sq_t);
  k_norm<<<dim3(16, PH, 2), 128, 0, stream>>>(src, tgt, sq_s, sq_t, Sq, Tq);
  k_gemm<<<NBLK3, 512, 0, stream>>>(Tq, Sq, rowPart, colPart);
  k_redloss<<<36, 256, 0, stream>>>(rowPart, colPart, sq_s, sq_t, part, ctr, out);
}